// Round 14
// baseline (197.886 us; speedup 1.0000x reference)
//
#include <hip/hip_runtime.h>
#include <math.h>

#define NRES 256
#define CDIM 8
#define HNUM 12
#define CS   384

typedef __attribute__((ext_vector_type(8))) short bf16x8;
typedef __attribute__((ext_vector_type(4))) float f32x4;
typedef unsigned short ushort_t;

static __device__ __forceinline__ unsigned short f2bf(float x) {
    unsigned int u = __float_as_uint(x);
    unsigned int r = (u + 0x7fffu + ((u >> 16) & 1u)) >> 16;
    return (unsigned short)r;
}

// ===========================================================================
// Kernel 0: conversions (LDS-tiled transposes) + bias packing + LayerNorm.
// Block map: [0,768) s->bf16 | [768,876) wt tiles | [876,912) wtg tiles |
//            [912,966) wo hi/lo tiles | [966] biases | [967,1223) LN rows
// ===========================================================================
#define TSTR 66   // ushort tile stride (33 words: conflict-free on write)
#define FSTR 65   // float tile stride (conflict-free on read-out)
__global__ __launch_bounds__(256) void convert_ln_kernel(
    const float* __restrict__ s,
    const float* __restrict__ wq, const float* __restrict__ bq,
    const float* __restrict__ wkv, const float* __restrict__ bkv,
    const float* __restrict__ wqp, const float* __restrict__ bqp,
    const float* __restrict__ wkvp, const float* __restrict__ bkvp,
    const float* __restrict__ wgq, const float* __restrict__ bgq,
    const float* __restrict__ wgk, const float* __restrict__ bgk,
    const float* __restrict__ wout,
    const float* __restrict__ g_gamma, const float* __restrict__ g_beta,
    ushort_t* __restrict__ s_bf, ushort_t* __restrict__ wt_bf,
    ushort_t* __restrict__ wtg_bf, float* __restrict__ pbias,
    float* __restrict__ gbias,
    ushort_t* __restrict__ wo_hi, ushort_t* __restrict__ wo_lo,
    ushort_t* __restrict__ sgn_bf)
{
    __shared__ ushort_t tile[64*TSTR];   // 8.4 KB
    __shared__ float ftile[64*FSTR];     // 16.6 KB
    __shared__ float sg[CS];
    __shared__ float red[256];
    const int tid = threadIdx.x;
    const int b = blockIdx.x;

    if (b < 768) {
        // ---- s -> bf16, vectorized ----
        const int idx = b*256 + tid;
        const float4 v = ((const float4*)s)[idx];
        unsigned int p0 = (unsigned int)f2bf(v.x) | ((unsigned int)f2bf(v.y) << 16);
        unsigned int p1 = (unsigned int)f2bf(v.z) | ((unsigned int)f2bf(v.w) << 16);
        uint2 pk; pk.x = p0; pk.y = p1;
        *(uint2*)&s_bf[(size_t)idx*4] = pk;
        return;
    }
    if (b < 876) {
        // ---- wt transpose: out wt_bf[vc][k], 64x64 tile ----
        const int t = b - 768;
        const int vt = t / 6, kt = t - vt*6;
        const int vc0 = vt*64, k0 = kt*64;
        #pragma unroll
        for (int it = 0; it < 16; ++it) {
            const int kk = it*4 + (tid >> 6);
            const int vv = tid & 63;
            const int vc = vc0 + vv;
            const float* w; int C, lc;
            if (vc < 192)      { w = wq;   C = 192; lc = vc; }
            else if (vc < 576) { w = wkv;  C = 384; lc = vc - 192; }
            else if (vc < 720) { w = wqp;  C = 144; lc = vc - 576; }
            else               { w = wkvp; C = 432; lc = vc - 720; }
            tile[vv*TSTR + kk] = f2bf(w[(size_t)(k0+kk)*C + lc]);
        }
        __syncthreads();
        #pragma unroll
        for (int it = 0; it < 16; ++it) {
            const int vv = it*4 + (tid >> 6);
            const int kk = tid & 63;
            wt_bf[(size_t)(vc0+vv)*384 + k0 + kk] = tile[vv*TSTR + kk];
        }
        return;
    }
    if (b < 912) {
        // ---- wtg transpose: out wtg_bf[vc][k] (vc<192 wgq else wgk) ----
        const int t = b - 876;
        const int vt = t / 6, kt = t - vt*6;
        const int vc0 = vt*64, k0 = kt*64;
        #pragma unroll
        for (int it = 0; it < 16; ++it) {
            const int kk = it*4 + (tid >> 6);
            const int vv = tid & 63;
            const int vc = vc0 + vv;
            const float val = (vc < 192) ? wgq[(size_t)(k0+kk)*192 + vc]
                                         : wgk[(size_t)(k0+kk)*192 + vc - 192];
            tile[vv*TSTR + kk] = f2bf(val);
        }
        __syncthreads();
        #pragma unroll
        for (int it = 0; it < 16; ++it) {
            const int vv = it*4 + (tid >> 6);
            const int kk = tid & 63;
            wtg_bf[(size_t)(vc0+vv)*384 + k0 + kk] = tile[vv*TSTR + kk];
        }
        return;
    }
    if (b < 966) {
        // ---- wout transpose hi/lo: out [n][k], src wout[k*384+n], K=576 ----
        const int t = b - 912;
        const int nt = t / 9, kt = t - nt*9;
        const int n0 = nt*64, k0 = kt*64;
        #pragma unroll
        for (int it = 0; it < 16; ++it) {
            const int kk = it*4 + (tid >> 6);
            const int nn = tid & 63;
            ftile[nn*FSTR + kk] = wout[(size_t)(k0+kk)*384 + n0 + nn];
        }
        __syncthreads();
        #pragma unroll
        for (int it = 0; it < 16; ++it) {
            const int nn = it*4 + (tid >> 6);
            const int kk = tid & 63;
            const float wv = ftile[nn*FSTR + kk];
            const unsigned int u = __float_as_uint(wv);
            const float hif = __uint_as_float(u & 0xFFFF0000u);
            wo_hi[(size_t)(n0+nn)*576 + k0 + kk] = (ushort_t)(u >> 16);
            wo_lo[(size_t)(n0+nn)*576 + k0 + kk] =
                (ushort_t)(__float_as_uint(wv - hif) >> 16);
        }
        return;
    }
    if (b == 966) {
        // ---- biases ----
        for (int i = tid; i < 1536; i += 256) {
            if (i < 1152) {
                float bb;
                if (i < 192)      bb = bq[i];
                else if (i < 576) bb = bkv[i - 192];
                else if (i < 720) bb = bqp[i - 576];
                else              bb = bkvp[i - 720];
                pbias[i] = bb;
            } else {
                const int g = i - 1152;
                gbias[g] = (g < 192) ? bgq[g] : bgk[g - 192];
            }
        }
        return;
    }

    // ---- LayerNorm branch: one block per n ----
    const int n = b - 967;
    for (int d = tid; d < CS; d += 256) {
        float acc = 0.f;
        for (int c = 0; c < CDIM; ++c) acc += s[((size_t)c*NRES+n)*CS + d];
        sg[d] = acc * (1.0f/CDIM);
    }
    __syncthreads();

    float lsum = 0.f;
    for (int d = tid; d < CS; d += 256) lsum += sg[d];
    red[tid] = lsum; __syncthreads();
    for (int st = 128; st > 0; st >>= 1) { if (tid < st) red[tid] += red[tid+st]; __syncthreads(); }
    const float mean = red[0] * (1.0f/CS);
    __syncthreads();

    float lvar = 0.f;
    for (int d = tid; d < CS; d += 256) { float df = sg[d]-mean; lvar += df*df; }
    red[tid] = lvar; __syncthreads();
    for (int st = 128; st > 0; st >>= 1) { if (tid < st) red[tid] += red[tid+st]; __syncthreads(); }
    const float var = red[0] * (1.0f/CS);
    __syncthreads();

    const float inv = rsqrtf(var + 1e-5f);
    for (int d = tid; d < CS; d += 256)
        sgn_bf[(size_t)n*CS + d] = f2bf((sg[d]-mean)*inv*g_gamma[d] + g_beta[d]);
}

// ===========================================================================
// Kernel 1: projection GEMM + g-projection GEMM fused (branch on block).
// ===========================================================================
__global__ __launch_bounds__(256) void proj_ggemm_kernel(
    const ushort_t* __restrict__ s_bf, const ushort_t* __restrict__ wt_bf,
    const float* __restrict__ pbias,
    const ushort_t* __restrict__ sgn_bf, const ushort_t* __restrict__ wtg_bf,
    const float* __restrict__ gbias,
    float* __restrict__ qo, float* __restrict__ ko, float* __restrict__ vo,
    float* __restrict__ rawp, float* __restrict__ gqo, float* __restrict__ gko)
{
    const int tid = threadIdx.x;
    const int wave = tid >> 6, lane = tid & 63;
    const int wrow = wave >> 1, wcol = wave & 1;
    const int qd = lane >> 4, lr = lane & 15;

    if (blockIdx.x < 576) {
        const int blk = blockIdx.x;
        const int rt = blk / 18, ct = blk - rt*18;
        const int r0 = rt * 64, c0 = ct * 64;
        const int m0 = r0 + wrow*32, n0 = c0 + wcol*32;

        f32x4 acc00 = {0,0,0,0}, acc01 = {0,0,0,0}, acc10 = {0,0,0,0}, acc11 = {0,0,0,0};

        const ushort_t* a0p = s_bf  + (size_t)(m0 + lr)*384 + qd*8;
        const ushort_t* a1p = a0p + 16*384;
        const ushort_t* b0p = wt_bf + (size_t)(n0 + lr)*384 + qd*8;
        const ushort_t* b1p = b0p + 16*384;

        #pragma unroll
        for (int kk = 0; kk < 384; kk += 32) {
            const bf16x8 a0 = *(const bf16x8*)(a0p + kk);
            const bf16x8 a1 = *(const bf16x8*)(a1p + kk);
            const bf16x8 b0 = *(const bf16x8*)(b0p + kk);
            const bf16x8 b1 = *(const bf16x8*)(b1p + kk);
            acc00 = __builtin_amdgcn_mfma_f32_16x16x32_bf16(a0, b0, acc00, 0, 0, 0);
            acc01 = __builtin_amdgcn_mfma_f32_16x16x32_bf16(a0, b1, acc01, 0, 0, 0);
            acc10 = __builtin_amdgcn_mfma_f32_16x16x32_bf16(a1, b0, acc10, 0, 0, 0);
            acc11 = __builtin_amdgcn_mfma_f32_16x16x32_bf16(a1, b1, acc11, 0, 0, 0);
        }

        #pragma unroll
        for (int mt = 0; mt < 2; ++mt) {
            #pragma unroll
            for (int nt = 0; nt < 2; ++nt) {
                const f32x4 av = (mt==0) ? (nt==0 ? acc00 : acc01)
                                         : (nt==0 ? acc10 : acc11);
                const int col = n0 + nt*16 + lr;
                const float bb = pbias[col];
                #pragma unroll
                for (int reg = 0; reg < 4; ++reg) {
                    const int row = m0 + mt*16 + qd*4 + reg;
                    const float val = av[reg] + bb;
                    if (col < 192) {
                        qo[(size_t)row*192 + col] = val;
                    } else if (col < 576) {
                        const int lc = col - 192, h = lc >> 5, rm = lc & 31;
                        if (rm < 16) ko[(size_t)row*192 + h*16 + rm] = val;
                        else         vo[(size_t)row*192 + h*16 + rm - 16] = val;
                    } else {
                        rawp[(size_t)row*576 + col - 576] = val;
                    }
                }
            }
        }
        return;
    }

    // ---- ggemm branch ----
    const int blk = blockIdx.x - 576;
    const int rt = blk / 6, ct = blk - rt*6;
    const int r0 = rt * 64, c0 = ct * 64;
    const int m0 = r0 + wrow*32, n0 = c0 + wcol*32;

    f32x4 acc00 = {0,0,0,0}, acc01 = {0,0,0,0}, acc10 = {0,0,0,0}, acc11 = {0,0,0,0};

    const ushort_t* a0p = sgn_bf + (size_t)(m0 + lr)*384 + qd*8;
    const ushort_t* a1p = a0p + 16*384;
    const ushort_t* b0p = wtg_bf + (size_t)(n0 + lr)*384 + qd*8;
    const ushort_t* b1p = b0p + 16*384;

    #pragma unroll
    for (int kk = 0; kk < 384; kk += 32) {
        const bf16x8 a0 = *(const bf16x8*)(a0p + kk);
        const bf16x8 a1 = *(const bf16x8*)(a1p + kk);
        const bf16x8 b0 = *(const bf16x8*)(b0p + kk);
        const bf16x8 b1 = *(const bf16x8*)(b1p + kk);
        acc00 = __builtin_amdgcn_mfma_f32_16x16x32_bf16(a0, b0, acc00, 0, 0, 0);
        acc01 = __builtin_amdgcn_mfma_f32_16x16x32_bf16(a0, b1, acc01, 0, 0, 0);
        acc10 = __builtin_amdgcn_mfma_f32_16x16x32_bf16(a1, b0, acc10, 0, 0, 0);
        acc11 = __builtin_amdgcn_mfma_f32_16x16x32_bf16(a1, b1, acc11, 0, 0, 0);
    }

    #pragma unroll
    for (int mt = 0; mt < 2; ++mt) {
        #pragma unroll
        for (int nt = 0; nt < 2; ++nt) {
            const f32x4 av = (mt==0) ? (nt==0 ? acc00 : acc01)
                                     : (nt==0 ? acc10 : acc11);
            const int col = n0 + nt*16 + lr;
            const float bb = gbias[col];
            #pragma unroll
            for (int reg = 0; reg < 4; ++reg) {
                const int row = m0 + mt*16 + qd*4 + reg;
                const float val = av[reg] + bb;
                if (col < 192) gqo[(size_t)row*192 + col]       = val;
                else           gko[(size_t)row*192 + col - 192] = val;
            }
        }
    }
}

// ===========================================================================
// Kernel 2: attention via MFMA; q/k point transforms inline; A/B rows built
// in registers then stored as 12x ds_write_b128 (row base j*208B is 16B-aligned).
// ===========================================================================
#define BSTR 104
__global__ __launch_bounds__(256) void attn_mfma_kernel(
    const float* __restrict__ q, const float* __restrict__ k,
    const float* __restrict__ rawp, const float* __restrict__ rot,
    const float* __restrict__ g_q, const float* __restrict__ g_k,
    const float* __restrict__ trans, const float* __restrict__ mask,
    const float* __restrict__ head_weights, const float* __restrict__ wdist,
    const float* __restrict__ bdist, float* __restrict__ a_out)
{
    const int blk  = blockIdx.x;
    const int qtr  = blk & 3;
    const int ch   = blk >> 2;
    const int h    = ch % HNUM;
    const int c    = ch / HNUM;
    const int i0   = qtr * 64;
    const int tid  = threadIdx.x;

    __shared__ ushort_t Bsh[256*BSTR];   // 53.2 KB
    __shared__ ushort_t Ash[64*BSTR];    // 13.3 KB
    __shared__ float dsh[7*256];         // 7 KB
    __shared__ float msh[256];
    __shared__ float kn_sh[256];
    __shared__ float qn_sh[64];
    __shared__ float wdsh[12], bdsh[12];
    __shared__ float cpart[96];
    __shared__ float censh[3];

    msh[tid] = mask[c*NRES + tid];
    if (tid < 12) { wdsh[tid] = wdist[tid]; bdsh[tid] = bdist[tid]; }

    if (tid < 96) {
        const int coord = tid % 3, chunk = tid / 3;
        float sv = 0.f;
        for (int e = 0; e < 8; ++e)
            sv += trans[((size_t)c*NRES + chunk*8 + e)*3 + coord];
        cpart[tid] = sv;
    }
    __syncthreads();
    if (tid < 3) {
        float sv = 0.f;
        for (int e = 0; e < 32; ++e) sv += cpart[e*3 + tid];
        censh[tid] = sv * (1.0f/256.0f);
    }
    __syncthreads();

    const float s54   = 0.13608276348795434f;  // sqrt(1/54)
    const float scale = 0.14433756729740643f;  // sqrt(1/48)
    const float hwv = 0.5f * logf(1.0f + expf(head_weights[h])) * s54;
    const float sh  = sqrtf(2.0f * hwv);
    const float cx = censh[0], cy = censh[1], cz = censh[2];

    // --- build B rows in registers, vector-store to LDS ---
    {
        const int j = tid;
        const int grow = c*NRES + j;
        ushort_t rowv[96];
        const float4* kr4 = (const float4*)(k   + (size_t)grow*192 + h*16);
        const float4* gk4 = (const float4*)(g_k + (size_t)j*192 + h*16);
        #pragma unroll
        for (int e4 = 0; e4 < 4; ++e4) {
            const float4 w = kr4[e4];
            rowv[e4*4+0] = f2bf(w.x); rowv[e4*4+1] = f2bf(w.y);
            rowv[e4*4+2] = f2bf(w.z); rowv[e4*4+3] = f2bf(w.w);
        }
        #pragma unroll
        for (int e4 = 0; e4 < 4; ++e4) {
            const float4 w = gk4[e4];
            rowv[16+e4*4+0] = f2bf(w.x); rowv[16+e4*4+1] = f2bf(w.y);
            rowv[16+e4*4+2] = f2bf(w.z); rowv[16+e4*4+3] = f2bf(w.w);
        }
        const float* base = rawp + (size_t)grow*576;
        const float4 rx = *(const float4*)(base + 144 + h*12);
        const float4 ry = *(const float4*)(base + 288 + h*12);
        const float4 rz = *(const float4*)(base + 432 + h*12);
        const float* R = rot + (size_t)grow*9;
        const float* T = trans + (size_t)grow*3;
        const float R0=R[0],R1=R[1],R2=R[2],R3=R[3],R4=R[4],R5=R[5],R6=R[6],R7=R[7],R8=R[8];
        const float Tx=T[0]-cx, Ty=T[1]-cy, Tz=T[2]-cz;
        const float xs[4] = {rx.x, rx.y, rx.z, rx.w};
        const float ys[4] = {ry.x, ry.y, ry.z, ry.w};
        const float zs[4] = {rz.x, rz.y, rz.z, rz.w};
        float kn = 0.f;
        #pragma unroll
        for (int pp = 0; pp < 4; ++pp) {
            const float x = xs[pp], y = ys[pp], z = zs[pp];
            const float pv[3] = { R0*x + R1*y + R2*z + Tx,
                                  R3*x + R4*y + R5*z + Ty,
                                  R6*x + R7*y + R8*z + Tz };
            #pragma unroll
            for (int cc = 0; cc < 3; ++cc) {
                const int e = pp*3 + cc;
                kn += pv[cc]*pv[cc];
                const float sp = sh * pv[cc];
                const unsigned int u = __float_as_uint(sp);
                const float hif = __uint_as_float(u & 0xFFFF0000u);
                const ushort_t hi = (ushort_t)(u >> 16);
                rowv[32+e] = hi;
                rowv[44+e] = (ushort_t)(__float_as_uint(sp - hif) >> 16);
                rowv[56+e] = hi;
            }
        }
        #pragma unroll
        for (int e = 68; e < 96; ++e) rowv[e] = 0;
        ushort_t* br = &Bsh[j*BSTR];
        #pragma unroll
        for (int e8 = 0; e8 < 12; ++e8)
            *(bf16x8*)(br + e8*8) = *(const bf16x8*)(rowv + e8*8);
        kn_sh[j] = hwv * kn;
    }

    // --- build A rows (threads 0..63) in registers, vector-store to LDS ---
    if (tid < 64) {
        const int il = i0 + tid;
        const int grow = c*NRES + il;
        ushort_t rowv[96];
        const float4* qr4 = (const float4*)(q   + (size_t)grow*192 + h*16);
        const float4* gq4 = (const float4*)(g_q + (size_t)il*192 + h*16);
        #pragma unroll
        for (int e4 = 0; e4 < 4; ++e4) {
            const float4 w = qr4[e4];
            rowv[e4*4+0] = f2bf(scale*w.x); rowv[e4*4+1] = f2bf(scale*w.y);
            rowv[e4*4+2] = f2bf(scale*w.z); rowv[e4*4+3] = f2bf(scale*w.w);
        }
        #pragma unroll
        for (int e4 = 0; e4 < 4; ++e4) {
            const float4 w = gq4[e4];
            rowv[16+e4*4+0] = f2bf(scale*w.x); rowv[16+e4*4+1] = f2bf(scale*w.y);
            rowv[16+e4*4+2] = f2bf(scale*w.z); rowv[16+e4*4+3] = f2bf(scale*w.w);
        }
        const float* base = rawp + (size_t)grow*576;
        const float4 rx = *(const float4*)(base + h*4);
        const float4 ry = *(const float4*)(base + 48 + h*4);
        const float4 rz = *(const float4*)(base + 96 + h*4);
        const float* R = rot + (size_t)grow*9;
        const float* T = trans + (size_t)grow*3;
        const float R0=R[0],R1=R[1],R2=R[2],R3=R[3],R4=R[4],R5=R[5],R6=R[6],R7=R[7],R8=R[8];
        const float Tx=T[0]-cx, Ty=T[1]-cy, Tz=T[2]-cz;
        const float xs[4] = {rx.x, rx.y, rx.z, rx.w};
        const float ys[4] = {ry.x, ry.y, ry.z, ry.w};
        const float zs[4] = {rz.x, rz.y, rz.z, rz.w};
        float qn = 0.f;
        #pragma unroll
        for (int pp = 0; pp < 4; ++pp) {
            const float x = xs[pp], y = ys[pp], z = zs[pp];
            const float pv[3] = { R0*x + R1*y + R2*z + Tx,
                                  R3*x + R4*y + R5*z + Ty,
                                  R6*x + R7*y + R8*z + Tz };
            #pragma unroll
            for (int cc = 0; cc < 3; ++cc) {
                const int e = pp*3 + cc;
                qn += pv[cc]*pv[cc];
                const float sp = sh * pv[cc];
                const unsigned int u = __float_as_uint(sp);
                const float hif = __uint_as_float(u & 0xFFFF0000u);
                const ushort_t hi = (ushort_t)(u >> 16);
                rowv[32+e] = hi;
                rowv[44+e] = hi;
                rowv[56+e] = (ushort_t)(__float_as_uint(sp - hif) >> 16);
            }
        }
        #pragma unroll
        for (int e = 68; e < 96; ++e) rowv[e] = 0;
        ushort_t* ar = &Ash[tid*BSTR];
        #pragma unroll
        for (int e8 = 0; e8 < 12; ++e8)
            *(bf16x8*)(ar + e8*8) = *(const bf16x8*)(rowv + e8*8);
        qn_sh[tid] = hwv * qn;
    }

    // --- dist LUT for this (h, i-quarter): NI <= 7 ---
    const int Fmin = h*65536 + i0*256;
    const int iibase = Fmin / 3072;
    const int NI = (Fmin + 63*256 + 255)/3072 - iibase + 1;
    const float* tch = trans + (size_t)c*768;
    for (int idx = tid; idx < NI*256; idx += 256) {
        const int e = idx >> 8, jj = idx & 255;
        const int ia = iibase + e;
        const float dx = tch[ia*3+0] - tch[jj*3+0];
        const float dy = tch[ia*3+1] - tch[jj*3+1];
        const float dz = tch[ia*3+2] - tch[jj*3+2];
        dsh[idx] = sqrtf(dx*dx + dy*dy + dz*dz);
    }
    __syncthreads();

    // --- main: wave handles 16 rows ---
    const int wave = tid >> 6, lane = tid & 63;
    const int qd = lane >> 4, lr = lane & 15;
    const int m0 = wave*16;

    const ushort_t* ap = &Ash[(m0 + lr)*BSTR + qd*8];
    const bf16x8 af0 = *(const bf16x8*)(ap);
    const bf16x8 af1 = *(const bf16x8*)(ap + 32);
    const bf16x8 af2 = *(const bf16x8*)(ap + 64);

    f32x4 acc[16];
    #pragma unroll
    for (int t = 0; t < 16; ++t) {
        const ushort_t* bp = &Bsh[(t*16 + lr)*BSTR + qd*8];
        f32x4 a = {0.f,0.f,0.f,0.f};
        a = __builtin_amdgcn_mfma_f32_16x16x32_bf16(af0, *(const bf16x8*)(bp),      a, 0, 0, 0);
        a = __builtin_amdgcn_mfma_f32_16x16x32_bf16(af1, *(const bf16x8*)(bp + 32), a, 0, 0, 0);
        a = __builtin_amdgcn_mfma_f32_16x16x32_bf16(af2, *(const bf16x8*)(bp + 64), a, 0, 0, 0);
        acc[t] = a;
    }

    const int ibase = m0 + qd*4;
    float qn_r[4], mb_r[4];
    int F0_[4];
    #pragma unroll
    for (int r = 0; r < 4; ++r) {
        const int il = i0 + ibase + r;
        qn_r[r] = qn_sh[ibase + r];
        mb_r[r] = 100000.0f * msh[il];
        F0_[r]  = h*65536 + il*256;
    }

    float mx[4] = {-1e30f,-1e30f,-1e30f,-1e30f};
    #pragma unroll
    for (int t = 0; t < 16; ++t) {
        const int j = t*16 + lr;
        const float knj = kn_sh[j];
        const float mj  = msh[j];
        #pragma unroll
        for (int r = 0; r < 4; ++r) {
            const unsigned int f = (unsigned int)(F0_[r] + j);
            const unsigned int p = f / 12u;
            const int ho = (int)(f - p*12u);
            const int ii = (int)(p >> 8);
            const int jj = (int)(p & 255u);
            const float dist = dsh[(ii - iibase)*256 + jj];
            const float db = dist*wdsh[ho] + bdsh[ho];
            const float lv = acc[t][r] - qn_r[r] - knj
                           + (mb_r[r]*mj - 100000.0f) + db;
            acc[t][r] = lv;
            mx[r] = fmaxf(mx[r], lv);
        }
    }
    #pragma unroll
    for (int r = 0; r < 4; ++r) {
        #pragma unroll
        for (int off = 1; off < 16; off <<= 1)
            mx[r] = fmaxf(mx[r], __shfl_xor(mx[r], off));
    }
    float sm[4] = {0.f,0.f,0.f,0.f};
    #pragma unroll
    for (int t = 0; t < 16; ++t) {
        #pragma unroll
        for (int r = 0; r < 4; ++r) {
            const float e = __expf(acc[t][r] - mx[r]);
            acc[t][r] = e;
            sm[r] += e;
        }
    }
    #pragma unroll
    for (int r = 0; r < 4; ++r) {
        #pragma unroll
        for (int off = 1; off < 16; off <<= 1)
            sm[r] += __shfl_xor(sm[r], off);
        sm[r] = 1.0f / sm[r];
    }
    float* dst = a_out + ((size_t)ch*NRES + (i0 + ibase))*NRES;
    #pragma unroll
    for (int t = 0; t < 16; ++t) {
        #pragma unroll
        for (int r = 0; r < 4; ++r)
            dst[(size_t)r*NRES + t*16 + lr] = acc[t][r]*sm[r];
    }
}

// ===========================================================================
// Kernel 3: o / o_pt via MFMA; v-point rigid transform applied INLINE.
// ===========================================================================
#define ASTRB 264
__global__ __launch_bounds__(256) void out_feat_mfma_kernel(
    const float* __restrict__ a, const float* __restrict__ v,
    const float* __restrict__ rawp, const float* __restrict__ rot,
    const float* __restrict__ trans,
    ushort_t* __restrict__ feat_hi, ushort_t* __restrict__ feat_lo)
{
    const int blk = blockIdx.x;
    const int qtr = blk & 3;
    const int ch  = blk >> 2;
    const int h   = ch % HNUM;
    const int c   = ch / HNUM;
    const int i0  = qtr * 64;
    const int tid = threadIdx.x;

    __shared__ ushort_t Bt[64*ASTRB];
    __shared__ float opt[64*25];
    __shared__ float osh[64*17];
    __shared__ float cpart[96];
    __shared__ float censh[3];

    if (tid < 96) {
        const int coord = tid % 3, chunk = tid / 3;
        float sv = 0.f;
        for (int e = 0; e < 8; ++e)
            sv += trans[((size_t)c*NRES + chunk*8 + e)*3 + coord];
        cpart[tid] = sv;
    }
    __syncthreads();
    if (tid < 3) {
        float sv = 0.f;
        for (int e = 0; e < 32; ++e) sv += cpart[e*3 + tid];
        censh[tid] = sv * (1.0f/256.0f);
    }
    __syncthreads();
    const float cx = censh[0], cy = censh[1], cz = censh[2];

    // stage B: thread j builds column j (v + inline-transformed v_pts hi/lo)
    {
        const int j = tid;
        const int grow = c*NRES + j;
        const float4* vr = (const float4*)(v + (size_t)grow*192 + h*16);
        #pragma unroll
        for (int e4 = 0; e4 < 4; ++e4) {
            const float4 w = vr[e4];
            Bt[(e4*4+0)*ASTRB + j] = f2bf(w.x);
            Bt[(e4*4+1)*ASTRB + j] = f2bf(w.y);
            Bt[(e4*4+2)*ASTRB + j] = f2bf(w.z);
            Bt[(e4*4+3)*ASTRB + j] = f2bf(w.w);
        }
        const float* base = rawp + (size_t)grow*576;
        const float4 rx0 = *(const float4*)(base + 144 + h*12 + 4);
        const float4 rx1 = *(const float4*)(base + 144 + h*12 + 8);
        const float4 ry0 = *(const float4*)(base + 288 + h*12 + 4);
        const float4 ry1 = *(const float4*)(base + 288 + h*12 + 8);
        const float4 rz0 = *(const float4*)(base + 432 + h*12 + 4);
        const float4 rz1 = *(const float4*)(base + 432 + h*12 + 8);
        const float* R = rot + (size_t)grow*9;
        const float* T = trans + (size_t)grow*3;
        const float R0=R[0],R1=R[1],R2=R[2],R3=R[3],R4=R[4],R5=R[5],R6=R[6],R7=R[7],R8=R[8];
        const float Tx=T[0]-cx, Ty=T[1]-cy, Tz=T[2]-cz;
        const float xs[8] = {rx0.x,rx0.y,rx0.z,rx0.w, rx1.x,rx1.y,rx1.z,rx1.w};
        const float ys[8] = {ry0.x,ry0.y,ry0.z,ry0.w, ry1.x,ry1.y,ry1.z,ry1.w};
        const float zs[8] = {rz0.x,rz0.y,rz0.z,rz0.w, rz1.x,rz1.y,rz1.z,rz1.w};
        #pragma unroll
        for (int pp = 0; pp < 8; ++pp) {
            const float x = xs[pp], y = ys[pp], z = zs[pp];
            const float pv[3] = { R0*x + R1*y + R2*z + Tx,
                                  R3*x + R4*y + R5*z + Ty,
                                  R6*x + R7*y + R8*z + Tz };
            #pragma unroll
            for (int cc = 0; cc < 3; ++cc) {
                const int e = pp*3 + cc;
                const float vp = pv[cc];
                const unsigned int u = __float_as_uint(vp);
                const float hif = __uint_as_float(u & 0xFFFF0000u);
                Bt[(16+e)*ASTRB + j] = (ushort_t)(u >> 16);
                Bt[(40+e)*ASTRB + j] = (ushort_t)(__float_as_uint(vp - hif) >> 16);
            }
        }
    }
    __syncthreads();

    const int wave = tid >> 6, lane = tid & 63;
    const int qd = lane >> 4, lr = lane & 15;
    const int m0 = wave*16;

    const float* arow = a + ((size_t)ch*NRES + i0 + m0 + lr)*NRES;

    f32x4 acc[4] = {{0,0,0,0},{0,0,0,0},{0,0,0,0},{0,0,0,0}};
    #pragma unroll
    for (int kk = 0; kk < 256; kk += 32) {
        const float4 a0 = *(const float4*)(arow + qd*8 + kk);
        const float4 a1 = *(const float4*)(arow + qd*8 + kk + 4);
        const float av[8] = {a0.x,a0.y,a0.z,a0.w,a1.x,a1.y,a1.z,a1.w};
        bf16x8 ahi, alo;
        #pragma unroll
        for (int e = 0; e < 8; ++e) {
            const unsigned int u = __float_as_uint(av[e]);
            const float hif = __uint_as_float(u & 0xFFFF0000u);
            ((ushort_t*)&ahi)[e] = (ushort_t)(u >> 16);
            ((ushort_t*)&alo)[e] = (ushort_t)(__float_as_uint(av[e] - hif) >> 16);
        }
        #pragma unroll
        for (int t = 0; t < 4; ++t) {
            const bf16x8 bf = *(const bf16x8*)&Bt[(t*16 + lr)*ASTRB + qd*8 + kk];
            acc[t] = __builtin_amdgcn_mfma_f32_16x16x32_bf16(ahi, bf, acc[t], 0, 0, 0);
            acc[t] = __builtin_amdgcn_mfma_f32_16x16x32_bf16(alo, bf, acc[t], 0, 0, 0);
        }
    }

    #pragma unroll
    for (int reg = 0; reg < 4; ++reg) {
        const int row_l = m0 + qd*4 + reg;
        osh[row_l*17 + lr] = acc[0][reg];
        opt[row_l*25 + lr] = acc[1][reg];
    }
    #pragma unroll
    for (int reg = 0; reg < 4; ++reg) {
        const int row_l = m0 + qd*4 + reg;
        if (lr < 8) opt[row_l*25 + 16 + lr] = acc[2][reg];
        else        opt[row_l*25 + (lr-8)] += acc[2][reg];
    }
    #pragma unroll
    for (int reg = 0; reg < 4; ++reg) {
        const int row_l = m0 + qd*4 + reg;
        opt[row_l*25 + 8 + lr] += acc[3][reg];
    }
    __syncthreads();

    #pragma unroll
    for (int it = 0; it < 4; ++it) {
        const int idx = it*256 + tid;
        const int row_l = idx >> 4, e = idx & 15;
        const int grow = c*NRES + i0 + row_l;
        const float val = osh[row_l*17 + e];
        const unsigned int u = __float_as_uint(val);
        const float hif = __uint_as_float(u & 0xFFFF0000u);
        feat_hi[(size_t)grow*576 + h*16 + e] = (ushort_t)(u >> 16);
        feat_lo[(size_t)grow*576 + h*16 + e] = (ushort_t)(__float_as_uint(val - hif) >> 16);
    }
    #pragma unroll
    for (int it = 0; it < 2; ++it) {
        const int idx = it*256 + tid;
        const int row_l = idx >> 3, p = idx & 7;
        const int grow = c*NRES + i0 + row_l;
        const float* R = rot + (size_t)grow*9;
        const float* T = trans + (size_t)grow*3;
        const float x = opt[row_l*25 + p*3+0] + cx - T[0];
        const float y = opt[row_l*25 + p*3+1] + cy - T[1];
        const float z = opt[row_l*25 + p*3+2] + cz - T[2];
        const float rx = R[0]*x + R[3]*y + R[6]*z;
        const float ry = R[1]*x + R[4]*y + R[7]*z;
        const float rz = R[2]*x + R[5]*y + R[8]*z;
        const float nm = sqrtf(rx*rx + ry*ry + rz*rz + 1e-8f);
        const float vals[4] = {rx, ry, rz, nm};
        #pragma unroll
        for (int sl = 0; sl < 4; ++sl) {
            const int col = 192 + sl*96 + h*8 + p;
            const float vv = vals[sl];
            const unsigned int u = __float_as_uint(vv);
            const float hif = __uint_as_float(u & 0xFFFF0000u);
            feat_hi[(size_t)grow*576 + col] = (ushort_t)(u >> 16);
            feat_lo[(size_t)grow*576 + col] = (ushort_t)(__float_as_uint(vv - hif) >> 16);
        }
    }
}

// ===========================================================================
// Kernel 4: out0 = feat @ wout + bout via MFMA (3-term hi/lo product).
// ===========================================================================
__global__ __launch_bounds__(256) void out_gemm_mfma_kernel(
    const ushort_t* __restrict__ feat_hi, const ushort_t* __restrict__ feat_lo,
    const ushort_t* __restrict__ wo_hi, const ushort_t* __restrict__ wo_lo,
    const float* __restrict__ bout, float* __restrict__ out0)
{
    const int blk = blockIdx.x;
    const int rt = blk / 6, ct = blk - rt*6;
    const int r0 = rt * 64, c0 = ct * 64;
    const int tid = threadIdx.x;
    const int wave = tid >> 6, lane = tid & 63;
    const int wrow = wave >> 1, wcol = wave & 1;
    const int m0 = r0 + wrow*32, n0 = c0 + wcol*32;
    const int qd = lane >> 4, lr = lane & 15;

    f32x4 acc[2][2] = {{{0,0,0,0},{0,0,0,0}},{{0,0,0,0},{0,0,0,0}}};

    const ushort_t* ah0 = feat_hi + (size_t)(m0 + lr)*576 + qd*8;
    const ushort_t* ah1 = ah0 + 16*576;
    const ushort_t* al0 = feat_lo + (size_t)(m0 + lr)*576 + qd*8;
    const ushort_t* al1 = al0 + 16*576;
    const ushort_t* bh0 = wo_hi + (size_t)(n0 + lr)*576 + qd*8;
    const ushort_t* bh1 = bh0 + 16*576;
    const ushort_t* bl0 = wo_lo + (size_t)(n0 + lr)*576 + qd*8;
    const ushort_t* bl1 = bl0 + 16*576;

    for (int kk = 0; kk < 576; kk += 32) {
        const bf16x8 fh0 = *(const bf16x8*)(ah0 + kk);
        const bf16x8 fh1 = *(const bf16x8*)(ah1 + kk);
        const bf16x8 fl0 = *(const bf16x8*)(al0 + kk);
        const bf16x8 fl1 = *(const bf16x8*)(al1 + kk);
        const bf16x8 wh0 = *(const bf16x8*)(bh0 + kk);
        const bf16x8 wh1 = *(const bf16x8*)(bh1 + kk);
        const bf16x8 wl0 = *(const bf16x8*)(bl0 + kk);
        const bf16x8 wl1 = *(const bf16x8*)(bl1 + kk);
        acc[0][0] = __builtin_amdgcn_mfma_f32_16x16x32_bf16(fh0, wh0, acc[0][0], 0, 0, 0);
        acc[0][1] = __builtin_amdgcn_mfma_f32_16x16x32_bf16(fh0, wh1, acc[0][1], 0, 0, 0);
        acc[1][0] = __builtin_amdgcn_mfma_f32_16x16x32_bf16(fh1, wh0, acc[1][0], 0, 0, 0);
        acc[1][1] = __builtin_amdgcn_mfma_f32_16x16x32_bf16(fh1, wh1, acc[1][1], 0, 0, 0);
        acc[0][0] = __builtin_amdgcn_mfma_f32_16x16x32_bf16(fl0, wh0, acc[0][0], 0, 0, 0);
        acc[0][1] = __builtin_amdgcn_mfma_f32_16x16x32_bf16(fl0, wh1, acc[0][1], 0, 0, 0);
        acc[1][0] = __builtin_amdgcn_mfma_f32_16x16x32_bf16(fl1, wh0, acc[1][0], 0, 0, 0);
        acc[1][1] = __builtin_amdgcn_mfma_f32_16x16x32_bf16(fl1, wh1, acc[1][1], 0, 0, 0);
        acc[0][0] = __builtin_amdgcn_mfma_f32_16x16x32_bf16(fh0, wl0, acc[0][0], 0, 0, 0);
        acc[0][1] = __builtin_amdgcn_mfma_f32_16x16x32_bf16(fh0, wl1, acc[0][1], 0, 0, 0);
        acc[1][0] = __builtin_amdgcn_mfma_f32_16x16x32_bf16(fh1, wl0, acc[1][0], 0, 0, 0);
        acc[1][1] = __builtin_amdgcn_mfma_f32_16x16x32_bf16(fh1, wl1, acc[1][1], 0, 0, 0);
    }

    #pragma unroll
    for (int mt = 0; mt < 2; ++mt) {
        #pragma unroll
        for (int nt = 0; nt < 2; ++nt) {
            const int col = n0 + nt*16 + lr;
            const float bb = bout[col];
            #pragma unroll
            for (int reg = 0; reg < 4; ++reg) {
                const int row = m0 + mt*16 + qd*4 + reg;
                out0[(size_t)row*CS + col] = acc[mt][nt][reg] + bb;
            }
        }
    }
}

// ===========================================================================
extern "C" void kernel_launch(void* const* d_in, const int* in_sizes, int n_in,
                              void* d_out, int out_size, void* d_ws, size_t ws_size,
                              hipStream_t stream)
{
    const float* s     = (const float*)d_in[0];
    const float* rot   = (const float*)d_in[2];
    const float* trans = (const float*)d_in[3];
    const float* mask  = (const float*)d_in[4];
    const float* wq    = (const float*)d_in[5];
    const float* bq    = (const float*)d_in[6];
    const float* wkv   = (const float*)d_in[7];
    const float* bkv   = (const float*)d_in[8];
    const float* g_gamma = (const float*)d_in[9];
    const float* g_beta  = (const float*)d_in[10];
    const float* wgq   = (const float*)d_in[11];
    const float* bgq   = (const float*)d_in[12];
    const float* wgk   = (const float*)d_in[13];
    const float* bgk   = (const float*)d_in[14];
    const float* wqp   = (const float*)d_in[15];
    const float* bqp   = (const float*)d_in[16];
    const float* wkvp  = (const float*)d_in[17];
    const float* bkvp  = (const float*)d_in[18];
    const float* head_weights = (const float*)d_in[19];
    const float* wdist = (const float*)d_in[20];
    const float* bdist = (const float*)d_in[21];
    const float* wout  = (const float*)d_in[22];
    const float* bout  = (const float*)d_in[23];

    float* ws      = (float*)d_ws;
    float* q_buf   = ws + 0;          // 393216
    float* gq_buf  = ws + 983040;     // 49152
    float* gk_buf  = ws + 1032192;    // 49152
    float* k_buf   = ws + 1081344;    // 393216
    float* v_buf   = ws + 1474560;    // 393216
    ushort_t* sgn_bf  = (ushort_t*)(ws + 1867776); // 98304 bf16
    ushort_t* feat_hi = (ushort_t*)(ws + 2457600); // 1179648 bf16
    ushort_t* feat_lo = (ushort_t*)(ws + 3047424); // 1179648 bf16
    ushort_t* wo_hi   = (ushort_t*)(ws + 3637248); // 221184 bf16
    ushort_t* wo_lo   = (ushort_t*)(ws + 3747840); // 221184 bf16
    float*    rawp    = ws + 4194304;              // 1179648 floats (private)

    float* out0  = (float*)d_out;       // 786432
    float* a_out = out0 + 786432;       // 6291456
    // overlays inside a_out (dead before attn writes):
    ushort_t* s_bf   = (ushort_t*)(a_out);                 // 786432 bf16
    ushort_t* wt_bf  = (ushort_t*)(a_out + 393216);        // 442368 bf16
    ushort_t* wtg_bf = (ushort_t*)(a_out + 614400);        // 147456 bf16
    float*    pbias  = a_out + 688128;                     // 1152
    float*    gbias  = a_out + 689280;                     // 384

    convert_ln_kernel<<<1223, 256, 0, stream>>>(s, wq, bq, wkv, bkv, wqp, bqp,
                                                wkvp, bkvp, wgq, bgq, wgk, bgk,
                                                wout, g_gamma, g_beta,
                                                s_bf, wt_bf, wtg_bf, pbias, gbias,
                                                wo_hi, wo_lo, sgn_bf);
    proj_ggemm_kernel<<<600, 256, 0, stream>>>(s_bf, wt_bf, pbias,
                                               sgn_bf, wtg_bf, gbias,
                                               q_buf, k_buf, v_buf, rawp,
                                               gq_buf, gk_buf);
    attn_mfma_kernel<<<384, 256, 0, stream>>>(q_buf, k_buf, rawp, rot,
                                              gq_buf, gk_buf, trans, mask,
                                              head_weights, wdist, bdist, a_out);
    out_feat_mfma_kernel<<<384, 256, 0, stream>>>(a_out, v_buf, rawp, rot, trans,
                                                  feat_hi, feat_lo);
    out_gemm_mfma_kernel<<<192, 256, 0, stream>>>(feat_hi, feat_lo, wo_hi, wo_lo,
                                                  bout, out0);
}

// Round 16
// 196.361 us; speedup vs baseline: 1.0078x; 1.0078x over previous
//
#include <hip/hip_runtime.h>
#include <math.h>

#define NRES 256
#define CDIM 8
#define HNUM 12
#define CS   384

typedef __attribute__((ext_vector_type(8))) short bf16x8;
typedef __attribute__((ext_vector_type(4))) float f32x4;
typedef unsigned short ushort_t;

static __device__ __forceinline__ unsigned short f2bf(float x) {
    unsigned int u = __float_as_uint(x);
    unsigned int r = (u + 0x7fffu + ((u >> 16) & 1u)) >> 16;
    return (unsigned short)r;
}

// ===========================================================================
// Kernel 0: conversions (LDS-tiled transposes) + bias packing + LayerNorm.
// ===========================================================================
#define TSTR 66
#define FSTR 65
__global__ __launch_bounds__(256) void convert_ln_kernel(
    const float* __restrict__ s,
    const float* __restrict__ wq, const float* __restrict__ bq,
    const float* __restrict__ wkv, const float* __restrict__ bkv,
    const float* __restrict__ wqp, const float* __restrict__ bqp,
    const float* __restrict__ wkvp, const float* __restrict__ bkvp,
    const float* __restrict__ wgq, const float* __restrict__ bgq,
    const float* __restrict__ wgk, const float* __restrict__ bgk,
    const float* __restrict__ wout,
    const float* __restrict__ g_gamma, const float* __restrict__ g_beta,
    ushort_t* __restrict__ s_bf, ushort_t* __restrict__ wt_bf,
    ushort_t* __restrict__ wtg_bf, float* __restrict__ pbias,
    float* __restrict__ gbias,
    ushort_t* __restrict__ wo_hi, ushort_t* __restrict__ wo_lo,
    ushort_t* __restrict__ sgn_bf)
{
    __shared__ ushort_t tile[64*TSTR];
    __shared__ float ftile[64*FSTR];
    __shared__ float sg[CS];
    __shared__ float red[256];
    const int tid = threadIdx.x;
    const int b = blockIdx.x;

    if (b < 768) {
        const int idx = b*256 + tid;
        const float4 v = ((const float4*)s)[idx];
        unsigned int p0 = (unsigned int)f2bf(v.x) | ((unsigned int)f2bf(v.y) << 16);
        unsigned int p1 = (unsigned int)f2bf(v.z) | ((unsigned int)f2bf(v.w) << 16);
        uint2 pk; pk.x = p0; pk.y = p1;
        *(uint2*)&s_bf[(size_t)idx*4] = pk;
        return;
    }
    if (b < 876) {
        const int t = b - 768;
        const int vt = t / 6, kt = t - vt*6;
        const int vc0 = vt*64, k0 = kt*64;
        #pragma unroll
        for (int it = 0; it < 16; ++it) {
            const int kk = it*4 + (tid >> 6);
            const int vv = tid & 63;
            const int vc = vc0 + vv;
            const float* w; int C, lc;
            if (vc < 192)      { w = wq;   C = 192; lc = vc; }
            else if (vc < 576) { w = wkv;  C = 384; lc = vc - 192; }
            else if (vc < 720) { w = wqp;  C = 144; lc = vc - 576; }
            else               { w = wkvp; C = 432; lc = vc - 720; }
            tile[vv*TSTR + kk] = f2bf(w[(size_t)(k0+kk)*C + lc]);
        }
        __syncthreads();
        #pragma unroll
        for (int it = 0; it < 16; ++it) {
            const int vv = it*4 + (tid >> 6);
            const int kk = tid & 63;
            wt_bf[(size_t)(vc0+vv)*384 + k0 + kk] = tile[vv*TSTR + kk];
        }
        return;
    }
    if (b < 912) {
        const int t = b - 876;
        const int vt = t / 6, kt = t - vt*6;
        const int vc0 = vt*64, k0 = kt*64;
        #pragma unroll
        for (int it = 0; it < 16; ++it) {
            const int kk = it*4 + (tid >> 6);
            const int vv = tid & 63;
            const int vc = vc0 + vv;
            const float val = (vc < 192) ? wgq[(size_t)(k0+kk)*192 + vc]
                                         : wgk[(size_t)(k0+kk)*192 + vc - 192];
            tile[vv*TSTR + kk] = f2bf(val);
        }
        __syncthreads();
        #pragma unroll
        for (int it = 0; it < 16; ++it) {
            const int vv = it*4 + (tid >> 6);
            const int kk = tid & 63;
            wtg_bf[(size_t)(vc0+vv)*384 + k0 + kk] = tile[vv*TSTR + kk];
        }
        return;
    }
    if (b < 966) {
        const int t = b - 912;
        const int nt = t / 9, kt = t - nt*9;
        const int n0 = nt*64, k0 = kt*64;
        #pragma unroll
        for (int it = 0; it < 16; ++it) {
            const int kk = it*4 + (tid >> 6);
            const int nn = tid & 63;
            ftile[nn*FSTR + kk] = wout[(size_t)(k0+kk)*384 + n0 + nn];
        }
        __syncthreads();
        #pragma unroll
        for (int it = 0; it < 16; ++it) {
            const int nn = it*4 + (tid >> 6);
            const int kk = tid & 63;
            const float wv = ftile[nn*FSTR + kk];
            const unsigned int u = __float_as_uint(wv);
            const float hif = __uint_as_float(u & 0xFFFF0000u);
            wo_hi[(size_t)(n0+nn)*576 + k0 + kk] = (ushort_t)(u >> 16);
            wo_lo[(size_t)(n0+nn)*576 + k0 + kk] =
                (ushort_t)(__float_as_uint(wv - hif) >> 16);
        }
        return;
    }
    if (b == 966) {
        for (int i = tid; i < 1536; i += 256) {
            if (i < 1152) {
                float bb;
                if (i < 192)      bb = bq[i];
                else if (i < 576) bb = bkv[i - 192];
                else if (i < 720) bb = bqp[i - 576];
                else              bb = bkvp[i - 720];
                pbias[i] = bb;
            } else {
                const int g = i - 1152;
                gbias[g] = (g < 192) ? bgq[g] : bgk[g - 192];
            }
        }
        return;
    }

    const int n = b - 967;
    for (int d = tid; d < CS; d += 256) {
        float acc = 0.f;
        for (int c = 0; c < CDIM; ++c) acc += s[((size_t)c*NRES+n)*CS + d];
        sg[d] = acc * (1.0f/CDIM);
    }
    __syncthreads();

    float lsum = 0.f;
    for (int d = tid; d < CS; d += 256) lsum += sg[d];
    red[tid] = lsum; __syncthreads();
    for (int st = 128; st > 0; st >>= 1) { if (tid < st) red[tid] += red[tid+st]; __syncthreads(); }
    const float mean = red[0] * (1.0f/CS);
    __syncthreads();

    float lvar = 0.f;
    for (int d = tid; d < CS; d += 256) { float df = sg[d]-mean; lvar += df*df; }
    red[tid] = lvar; __syncthreads();
    for (int st = 128; st > 0; st >>= 1) { if (tid < st) red[tid] += red[tid+st]; __syncthreads(); }
    const float var = red[0] * (1.0f/CS);
    __syncthreads();

    const float inv = rsqrtf(var + 1e-5f);
    for (int d = tid; d < CS; d += 256)
        sgn_bf[(size_t)n*CS + d] = f2bf((sg[d]-mean)*inv*g_gamma[d] + g_beta[d]);
}

// ===========================================================================
// Kernel 1: projection GEMM + g-projection GEMM fused (branch on block).
// ===========================================================================
__global__ __launch_bounds__(256) void proj_ggemm_kernel(
    const ushort_t* __restrict__ s_bf, const ushort_t* __restrict__ wt_bf,
    const float* __restrict__ pbias,
    const ushort_t* __restrict__ sgn_bf, const ushort_t* __restrict__ wtg_bf,
    const float* __restrict__ gbias,
    float* __restrict__ qo, float* __restrict__ ko, float* __restrict__ vo,
    float* __restrict__ rawp, float* __restrict__ gqo, float* __restrict__ gko)
{
    const int tid = threadIdx.x;
    const int wave = tid >> 6, lane = tid & 63;
    const int wrow = wave >> 1, wcol = wave & 1;
    const int qd = lane >> 4, lr = lane & 15;

    if (blockIdx.x < 576) {
        const int blk = blockIdx.x;
        const int rt = blk / 18, ct = blk - rt*18;
        const int r0 = rt * 64, c0 = ct * 64;
        const int m0 = r0 + wrow*32, n0 = c0 + wcol*32;

        f32x4 acc00 = {0,0,0,0}, acc01 = {0,0,0,0}, acc10 = {0,0,0,0}, acc11 = {0,0,0,0};

        const ushort_t* a0p = s_bf  + (size_t)(m0 + lr)*384 + qd*8;
        const ushort_t* a1p = a0p + 16*384;
        const ushort_t* b0p = wt_bf + (size_t)(n0 + lr)*384 + qd*8;
        const ushort_t* b1p = b0p + 16*384;

        #pragma unroll
        for (int kk = 0; kk < 384; kk += 32) {
            const bf16x8 a0 = *(const bf16x8*)(a0p + kk);
            const bf16x8 a1 = *(const bf16x8*)(a1p + kk);
            const bf16x8 b0 = *(const bf16x8*)(b0p + kk);
            const bf16x8 b1 = *(const bf16x8*)(b1p + kk);
            acc00 = __builtin_amdgcn_mfma_f32_16x16x32_bf16(a0, b0, acc00, 0, 0, 0);
            acc01 = __builtin_amdgcn_mfma_f32_16x16x32_bf16(a0, b1, acc01, 0, 0, 0);
            acc10 = __builtin_amdgcn_mfma_f32_16x16x32_bf16(a1, b0, acc10, 0, 0, 0);
            acc11 = __builtin_amdgcn_mfma_f32_16x16x32_bf16(a1, b1, acc11, 0, 0, 0);
        }

        #pragma unroll
        for (int mt = 0; mt < 2; ++mt) {
            #pragma unroll
            for (int nt = 0; nt < 2; ++nt) {
                const f32x4 av = (mt==0) ? (nt==0 ? acc00 : acc01)
                                         : (nt==0 ? acc10 : acc11);
                const int col = n0 + nt*16 + lr;
                const float bb = pbias[col];
                #pragma unroll
                for (int reg = 0; reg < 4; ++reg) {
                    const int row = m0 + mt*16 + qd*4 + reg;
                    const float val = av[reg] + bb;
                    if (col < 192) {
                        qo[(size_t)row*192 + col] = val;
                    } else if (col < 576) {
                        const int lc = col - 192, h = lc >> 5, rm = lc & 31;
                        if (rm < 16) ko[(size_t)row*192 + h*16 + rm] = val;
                        else         vo[(size_t)row*192 + h*16 + rm - 16] = val;
                    } else {
                        rawp[(size_t)row*576 + col - 576] = val;
                    }
                }
            }
        }
        return;
    }

    const int blk = blockIdx.x - 576;
    const int rt = blk / 6, ct = blk - rt*6;
    const int r0 = rt * 64, c0 = ct * 64;
    const int m0 = r0 + wrow*32, n0 = c0 + wcol*32;

    f32x4 acc00 = {0,0,0,0}, acc01 = {0,0,0,0}, acc10 = {0,0,0,0}, acc11 = {0,0,0,0};

    const ushort_t* a0p = sgn_bf + (size_t)(m0 + lr)*384 + qd*8;
    const ushort_t* a1p = a0p + 16*384;
    const ushort_t* b0p = wtg_bf + (size_t)(n0 + lr)*384 + qd*8;
    const ushort_t* b1p = b0p + 16*384;

    #pragma unroll
    for (int kk = 0; kk < 384; kk += 32) {
        const bf16x8 a0 = *(const bf16x8*)(a0p + kk);
        const bf16x8 a1 = *(const bf16x8*)(a1p + kk);
        const bf16x8 b0 = *(const bf16x8*)(b0p + kk);
        const bf16x8 b1 = *(const bf16x8*)(b1p + kk);
        acc00 = __builtin_amdgcn_mfma_f32_16x16x32_bf16(a0, b0, acc00, 0, 0, 0);
        acc01 = __builtin_amdgcn_mfma_f32_16x16x32_bf16(a0, b1, acc01, 0, 0, 0);
        acc10 = __builtin_amdgcn_mfma_f32_16x16x32_bf16(a1, b0, acc10, 0, 0, 0);
        acc11 = __builtin_amdgcn_mfma_f32_16x16x32_bf16(a1, b1, acc11, 0, 0, 0);
    }

    #pragma unroll
    for (int mt = 0; mt < 2; ++mt) {
        #pragma unroll
        for (int nt = 0; nt < 2; ++nt) {
            const f32x4 av = (mt==0) ? (nt==0 ? acc00 : acc01)
                                     : (nt==0 ? acc10 : acc11);
            const int col = n0 + nt*16 + lr;
            const float bb = gbias[col];
            #pragma unroll
            for (int reg = 0; reg < 4; ++reg) {
                const int row = m0 + mt*16 + qd*4 + reg;
                const float val = av[reg] + bb;
                if (col < 192) gqo[(size_t)row*192 + col]       = val;
                else           gko[(size_t)row*192 + col - 192] = val;
            }
        }
    }
}

// ===========================================================================
// Kernel 2: attention via MFMA; a_out written with NON-TEMPORAL stores.
// ===========================================================================
#define BSTR 104
__global__ __launch_bounds__(256) void attn_mfma_kernel(
    const float* __restrict__ q, const float* __restrict__ k,
    const float* __restrict__ rawp, const float* __restrict__ rot,
    const float* __restrict__ g_q, const float* __restrict__ g_k,
    const float* __restrict__ trans, const float* __restrict__ mask,
    const float* __restrict__ head_weights, const float* __restrict__ wdist,
    const float* __restrict__ bdist, float* __restrict__ a_out)
{
    const int blk  = blockIdx.x;
    const int qtr  = blk & 3;
    const int ch   = blk >> 2;
    const int h    = ch % HNUM;
    const int c    = ch / HNUM;
    const int i0   = qtr * 64;
    const int tid  = threadIdx.x;

    __shared__ ushort_t Bsh[256*BSTR];
    __shared__ ushort_t Ash[64*BSTR];
    __shared__ float dsh[7*256];
    __shared__ float msh[256];
    __shared__ float kn_sh[256];
    __shared__ float qn_sh[64];
    __shared__ float wdsh[12], bdsh[12];
    __shared__ float cpart[96];
    __shared__ float censh[3];

    msh[tid] = mask[c*NRES + tid];
    if (tid < 12) { wdsh[tid] = wdist[tid]; bdsh[tid] = bdist[tid]; }

    if (tid < 96) {
        const int coord = tid % 3, chunk = tid / 3;
        float sv = 0.f;
        for (int e = 0; e < 8; ++e)
            sv += trans[((size_t)c*NRES + chunk*8 + e)*3 + coord];
        cpart[tid] = sv;
    }
    __syncthreads();
    if (tid < 3) {
        float sv = 0.f;
        for (int e = 0; e < 32; ++e) sv += cpart[e*3 + tid];
        censh[tid] = sv * (1.0f/256.0f);
    }
    __syncthreads();

    const float s54   = 0.13608276348795434f;
    const float scale = 0.14433756729740643f;
    const float hwv = 0.5f * logf(1.0f + expf(head_weights[h])) * s54;
    const float sh  = sqrtf(2.0f * hwv);
    const float cx = censh[0], cy = censh[1], cz = censh[2];

    {
        const int j = tid;
        const int grow = c*NRES + j;
        ushort_t rowv[96];
        const float4* kr4 = (const float4*)(k   + (size_t)grow*192 + h*16);
        const float4* gk4 = (const float4*)(g_k + (size_t)j*192 + h*16);
        #pragma unroll
        for (int e4 = 0; e4 < 4; ++e4) {
            const float4 w = kr4[e4];
            rowv[e4*4+0] = f2bf(w.x); rowv[e4*4+1] = f2bf(w.y);
            rowv[e4*4+2] = f2bf(w.z); rowv[e4*4+3] = f2bf(w.w);
        }
        #pragma unroll
        for (int e4 = 0; e4 < 4; ++e4) {
            const float4 w = gk4[e4];
            rowv[16+e4*4+0] = f2bf(w.x); rowv[16+e4*4+1] = f2bf(w.y);
            rowv[16+e4*4+2] = f2bf(w.z); rowv[16+e4*4+3] = f2bf(w.w);
        }
        const float* base = rawp + (size_t)grow*576;
        const float4 rx = *(const float4*)(base + 144 + h*12);
        const float4 ry = *(const float4*)(base + 288 + h*12);
        const float4 rz = *(const float4*)(base + 432 + h*12);
        const float* R = rot + (size_t)grow*9;
        const float* T = trans + (size_t)grow*3;
        const float R0=R[0],R1=R[1],R2=R[2],R3=R[3],R4=R[4],R5=R[5],R6=R[6],R7=R[7],R8=R[8];
        const float Tx=T[0]-cx, Ty=T[1]-cy, Tz=T[2]-cz;
        const float xs[4] = {rx.x, rx.y, rx.z, rx.w};
        const float ys[4] = {ry.x, ry.y, ry.z, ry.w};
        const float zs[4] = {rz.x, rz.y, rz.z, rz.w};
        float kn = 0.f;
        #pragma unroll
        for (int pp = 0; pp < 4; ++pp) {
            const float x = xs[pp], y = ys[pp], z = zs[pp];
            const float pv[3] = { R0*x + R1*y + R2*z + Tx,
                                  R3*x + R4*y + R5*z + Ty,
                                  R6*x + R7*y + R8*z + Tz };
            #pragma unroll
            for (int cc = 0; cc < 3; ++cc) {
                const int e = pp*3 + cc;
                kn += pv[cc]*pv[cc];
                const float sp = sh * pv[cc];
                const unsigned int u = __float_as_uint(sp);
                const float hif = __uint_as_float(u & 0xFFFF0000u);
                const ushort_t hi = (ushort_t)(u >> 16);
                rowv[32+e] = hi;
                rowv[44+e] = (ushort_t)(__float_as_uint(sp - hif) >> 16);
                rowv[56+e] = hi;
            }
        }
        #pragma unroll
        for (int e = 68; e < 96; ++e) rowv[e] = 0;
        ushort_t* br = &Bsh[j*BSTR];
        #pragma unroll
        for (int e8 = 0; e8 < 12; ++e8)
            *(bf16x8*)(br + e8*8) = *(const bf16x8*)(rowv + e8*8);
        kn_sh[j] = hwv * kn;
    }

    if (tid < 64) {
        const int il = i0 + tid;
        const int grow = c*NRES + il;
        ushort_t rowv[96];
        const float4* qr4 = (const float4*)(q   + (size_t)grow*192 + h*16);
        const float4* gq4 = (const float4*)(g_q + (size_t)il*192 + h*16);
        #pragma unroll
        for (int e4 = 0; e4 < 4; ++e4) {
            const float4 w = qr4[e4];
            rowv[e4*4+0] = f2bf(scale*w.x); rowv[e4*4+1] = f2bf(scale*w.y);
            rowv[e4*4+2] = f2bf(scale*w.z); rowv[e4*4+3] = f2bf(scale*w.w);
        }
        #pragma unroll
        for (int e4 = 0; e4 < 4; ++e4) {
            const float4 w = gq4[e4];
            rowv[16+e4*4+0] = f2bf(scale*w.x); rowv[16+e4*4+1] = f2bf(scale*w.y);
            rowv[16+e4*4+2] = f2bf(scale*w.z); rowv[16+e4*4+3] = f2bf(scale*w.w);
        }
        const float* base = rawp + (size_t)grow*576;
        const float4 rx = *(const float4*)(base + h*4);
        const float4 ry = *(const float4*)(base + 48 + h*4);
        const float4 rz = *(const float4*)(base + 96 + h*4);
        const float* R = rot + (size_t)grow*9;
        const float* T = trans + (size_t)grow*3;
        const float R0=R[0],R1=R[1],R2=R[2],R3=R[3],R4=R[4],R5=R[5],R6=R[6],R7=R[7],R8=R[8];
        const float Tx=T[0]-cx, Ty=T[1]-cy, Tz=T[2]-cz;
        const float xs[4] = {rx.x, rx.y, rx.z, rx.w};
        const float ys[4] = {ry.x, ry.y, ry.z, ry.w};
        const float zs[4] = {rz.x, rz.y, rz.z, rz.w};
        float qn = 0.f;
        #pragma unroll
        for (int pp = 0; pp < 4; ++pp) {
            const float x = xs[pp], y = ys[pp], z = zs[pp];
            const float pv[3] = { R0*x + R1*y + R2*z + Tx,
                                  R3*x + R4*y + R5*z + Ty,
                                  R6*x + R7*y + R8*z + Tz };
            #pragma unroll
            for (int cc = 0; cc < 3; ++cc) {
                const int e = pp*3 + cc;
                qn += pv[cc]*pv[cc];
                const float sp = sh * pv[cc];
                const unsigned int u = __float_as_uint(sp);
                const float hif = __uint_as_float(u & 0xFFFF0000u);
                const ushort_t hi = (ushort_t)(u >> 16);
                rowv[32+e] = hi;
                rowv[44+e] = hi;
                rowv[56+e] = (ushort_t)(__float_as_uint(sp - hif) >> 16);
            }
        }
        #pragma unroll
        for (int e = 68; e < 96; ++e) rowv[e] = 0;
        ushort_t* ar = &Ash[tid*BSTR];
        #pragma unroll
        for (int e8 = 0; e8 < 12; ++e8)
            *(bf16x8*)(ar + e8*8) = *(const bf16x8*)(rowv + e8*8);
        qn_sh[tid] = hwv * qn;
    }

    const int Fmin = h*65536 + i0*256;
    const int iibase = Fmin / 3072;
    const int NI = (Fmin + 63*256 + 255)/3072 - iibase + 1;
    const float* tch = trans + (size_t)c*768;
    for (int idx = tid; idx < NI*256; idx += 256) {
        const int e = idx >> 8, jj = idx & 255;
        const int ia = iibase + e;
        const float dx = tch[ia*3+0] - tch[jj*3+0];
        const float dy = tch[ia*3+1] - tch[jj*3+1];
        const float dz = tch[ia*3+2] - tch[jj*3+2];
        dsh[idx] = sqrtf(dx*dx + dy*dy + dz*dz);
    }
    __syncthreads();

    const int wave = tid >> 6, lane = tid & 63;
    const int qd = lane >> 4, lr = lane & 15;
    const int m0 = wave*16;

    const ushort_t* ap = &Ash[(m0 + lr)*BSTR + qd*8];
    const bf16x8 af0 = *(const bf16x8*)(ap);
    const bf16x8 af1 = *(const bf16x8*)(ap + 32);
    const bf16x8 af2 = *(const bf16x8*)(ap + 64);

    f32x4 acc[16];
    #pragma unroll
    for (int t = 0; t < 16; ++t) {
        const ushort_t* bp = &Bsh[(t*16 + lr)*BSTR + qd*8];
        f32x4 a = {0.f,0.f,0.f,0.f};
        a = __builtin_amdgcn_mfma_f32_16x16x32_bf16(af0, *(const bf16x8*)(bp),      a, 0, 0, 0);
        a = __builtin_amdgcn_mfma_f32_16x16x32_bf16(af1, *(const bf16x8*)(bp + 32), a, 0, 0, 0);
        a = __builtin_amdgcn_mfma_f32_16x16x32_bf16(af2, *(const bf16x8*)(bp + 64), a, 0, 0, 0);
        acc[t] = a;
    }

    const int ibase = m0 + qd*4;
    float qn_r[4], mb_r[4];
    int F0_[4];
    #pragma unroll
    for (int r = 0; r < 4; ++r) {
        const int il = i0 + ibase + r;
        qn_r[r] = qn_sh[ibase + r];
        mb_r[r] = 100000.0f * msh[il];
        F0_[r]  = h*65536 + il*256;
    }

    float mx[4] = {-1e30f,-1e30f,-1e30f,-1e30f};
    #pragma unroll
    for (int t = 0; t < 16; ++t) {
        const int j = t*16 + lr;
        const float knj = kn_sh[j];
        const float mj  = msh[j];
        #pragma unroll
        for (int r = 0; r < 4; ++r) {
            const unsigned int f = (unsigned int)(F0_[r] + j);
            const unsigned int p = f / 12u;
            const int ho = (int)(f - p*12u);
            const int ii = (int)(p >> 8);
            const int jj = (int)(p & 255u);
            const float dist = dsh[(ii - iibase)*256 + jj];
            const float db = dist*wdsh[ho] + bdsh[ho];
            const float lv = acc[t][r] - qn_r[r] - knj
                           + (mb_r[r]*mj - 100000.0f) + db;
            acc[t][r] = lv;
            mx[r] = fmaxf(mx[r], lv);
        }
    }
    #pragma unroll
    for (int r = 0; r < 4; ++r) {
        #pragma unroll
        for (int off = 1; off < 16; off <<= 1)
            mx[r] = fmaxf(mx[r], __shfl_xor(mx[r], off));
    }
    float sm[4] = {0.f,0.f,0.f,0.f};
    #pragma unroll
    for (int t = 0; t < 16; ++t) {
        #pragma unroll
        for (int r = 0; r < 4; ++r) {
            const float e = __expf(acc[t][r] - mx[r]);
            acc[t][r] = e;
            sm[r] += e;
        }
    }
    #pragma unroll
    for (int r = 0; r < 4; ++r) {
        #pragma unroll
        for (int off = 1; off < 16; off <<= 1)
            sm[r] += __shfl_xor(sm[r], off);
        sm[r] = 1.0f / sm[r];
    }
    float* dst = a_out + ((size_t)ch*NRES + (i0 + ibase))*NRES;
    #pragma unroll
    for (int t = 0; t < 16; ++t) {
        #pragma unroll
        for (int r = 0; r < 4; ++r)
            __builtin_nontemporal_store(acc[t][r]*sm[r],
                                        dst + (size_t)r*NRES + t*16 + lr);
    }
}

// ===========================================================================
// Kernel 3: o / o_pt via MFMA; a read via non-temporal loads (native vec type).
// ===========================================================================
#define ASTRB 264
__global__ __launch_bounds__(256) void out_feat_mfma_kernel(
    const float* __restrict__ a, const float* __restrict__ v,
    const float* __restrict__ rawp, const float* __restrict__ rot,
    const float* __restrict__ trans,
    ushort_t* __restrict__ feat_hi, ushort_t* __restrict__ feat_lo)
{
    const int blk = blockIdx.x;
    const int qtr = blk & 3;
    const int ch  = blk >> 2;
    const int h   = ch % HNUM;
    const int c   = ch / HNUM;
    const int i0  = qtr * 64;
    const int tid = threadIdx.x;

    __shared__ ushort_t Bt[64*ASTRB];
    __shared__ float opt[64*25];
    __shared__ float osh[64*17];
    __shared__ float cpart[96];
    __shared__ float censh[3];

    if (tid < 96) {
        const int coord = tid % 3, chunk = tid / 3;
        float sv = 0.f;
        for (int e = 0; e < 8; ++e)
            sv += trans[((size_t)c*NRES + chunk*8 + e)*3 + coord];
        cpart[tid] = sv;
    }
    __syncthreads();
    if (tid < 3) {
        float sv = 0.f;
        for (int e = 0; e < 32; ++e) sv += cpart[e*3 + tid];
        censh[tid] = sv * (1.0f/256.0f);
    }
    __syncthreads();
    const float cx = censh[0], cy = censh[1], cz = censh[2];

    {
        const int j = tid;
        const int grow = c*NRES + j;
        const float4* vr = (const float4*)(v + (size_t)grow*192 + h*16);
        #pragma unroll
        for (int e4 = 0; e4 < 4; ++e4) {
            const float4 w = vr[e4];
            Bt[(e4*4+0)*ASTRB + j] = f2bf(w.x);
            Bt[(e4*4+1)*ASTRB + j] = f2bf(w.y);
            Bt[(e4*4+2)*ASTRB + j] = f2bf(w.z);
            Bt[(e4*4+3)*ASTRB + j] = f2bf(w.w);
        }
        const float* base = rawp + (size_t)grow*576;
        const float4 rx0 = *(const float4*)(base + 144 + h*12 + 4);
        const float4 rx1 = *(const float4*)(base + 144 + h*12 + 8);
        const float4 ry0 = *(const float4*)(base + 288 + h*12 + 4);
        const float4 ry1 = *(const float4*)(base + 288 + h*12 + 8);
        const float4 rz0 = *(const float4*)(base + 432 + h*12 + 4);
        const float4 rz1 = *(const float4*)(base + 432 + h*12 + 8);
        const float* R = rot + (size_t)grow*9;
        const float* T = trans + (size_t)grow*3;
        const float R0=R[0],R1=R[1],R2=R[2],R3=R[3],R4=R[4],R5=R[5],R6=R[6],R7=R[7],R8=R[8];
        const float Tx=T[0]-cx, Ty=T[1]-cy, Tz=T[2]-cz;
        const float xs[8] = {rx0.x,rx0.y,rx0.z,rx0.w, rx1.x,rx1.y,rx1.z,rx1.w};
        const float ys[8] = {ry0.x,ry0.y,ry0.z,ry0.w, ry1.x,ry1.y,ry1.z,ry1.w};
        const float zs[8] = {rz0.x,rz0.y,rz0.z,rz0.w, rz1.x,rz1.y,rz1.z,rz1.w};
        #pragma unroll
        for (int pp = 0; pp < 8; ++pp) {
            const float x = xs[pp], y = ys[pp], z = zs[pp];
            const float pv[3] = { R0*x + R1*y + R2*z + Tx,
                                  R3*x + R4*y + R5*z + Ty,
                                  R6*x + R7*y + R8*z + Tz };
            #pragma unroll
            for (int cc = 0; cc < 3; ++cc) {
                const int e = pp*3 + cc;
                const float vp = pv[cc];
                const unsigned int u = __float_as_uint(vp);
                const float hif = __uint_as_float(u & 0xFFFF0000u);
                Bt[(16+e)*ASTRB + j] = (ushort_t)(u >> 16);
                Bt[(40+e)*ASTRB + j] = (ushort_t)(__float_as_uint(vp - hif) >> 16);
            }
        }
    }
    __syncthreads();

    const int wave = tid >> 6, lane = tid & 63;
    const int qd = lane >> 4, lr = lane & 15;
    const int m0 = wave*16;

    const float* arow = a + ((size_t)ch*NRES + i0 + m0 + lr)*NRES;

    f32x4 acc[4] = {{0,0,0,0},{0,0,0,0},{0,0,0,0},{0,0,0,0}};
    #pragma unroll
    for (int kk = 0; kk < 256; kk += 32) {
        const f32x4 a0 = __builtin_nontemporal_load((const f32x4*)(arow + qd*8 + kk));
        const f32x4 a1 = __builtin_nontemporal_load((const f32x4*)(arow + qd*8 + kk + 4));
        const float av[8] = {a0[0],a0[1],a0[2],a0[3],a1[0],a1[1],a1[2],a1[3]};
        bf16x8 ahi, alo;
        #pragma unroll
        for (int e = 0; e < 8; ++e) {
            const unsigned int u = __float_as_uint(av[e]);
            const float hif = __uint_as_float(u & 0xFFFF0000u);
            ((ushort_t*)&ahi)[e] = (ushort_t)(u >> 16);
            ((ushort_t*)&alo)[e] = (ushort_t)(__float_as_uint(av[e] - hif) >> 16);
        }
        #pragma unroll
        for (int t = 0; t < 4; ++t) {
            const bf16x8 bf = *(const bf16x8*)&Bt[(t*16 + lr)*ASTRB + qd*8 + kk];
            acc[t] = __builtin_amdgcn_mfma_f32_16x16x32_bf16(ahi, bf, acc[t], 0, 0, 0);
            acc[t] = __builtin_amdgcn_mfma_f32_16x16x32_bf16(alo, bf, acc[t], 0, 0, 0);
        }
    }

    #pragma unroll
    for (int reg = 0; reg < 4; ++reg) {
        const int row_l = m0 + qd*4 + reg;
        osh[row_l*17 + lr] = acc[0][reg];
        opt[row_l*25 + lr] = acc[1][reg];
    }
    #pragma unroll
    for (int reg = 0; reg < 4; ++reg) {
        const int row_l = m0 + qd*4 + reg;
        if (lr < 8) opt[row_l*25 + 16 + lr] = acc[2][reg];
        else        opt[row_l*25 + (lr-8)] += acc[2][reg];
    }
    #pragma unroll
    for (int reg = 0; reg < 4; ++reg) {
        const int row_l = m0 + qd*4 + reg;
        opt[row_l*25 + 8 + lr] += acc[3][reg];
    }
    __syncthreads();

    #pragma unroll
    for (int it = 0; it < 4; ++it) {
        const int idx = it*256 + tid;
        const int row_l = idx >> 4, e = idx & 15;
        const int grow = c*NRES + i0 + row_l;
        const float val = osh[row_l*17 + e];
        const unsigned int u = __float_as_uint(val);
        const float hif = __uint_as_float(u & 0xFFFF0000u);
        feat_hi[(size_t)grow*576 + h*16 + e] = (ushort_t)(u >> 16);
        feat_lo[(size_t)grow*576 + h*16 + e] = (ushort_t)(__float_as_uint(val - hif) >> 16);
    }
    #pragma unroll
    for (int it = 0; it < 2; ++it) {
        const int idx = it*256 + tid;
        const int row_l = idx >> 3, p = idx & 7;
        const int grow = c*NRES + i0 + row_l;
        const float* R = rot + (size_t)grow*9;
        const float* T = trans + (size_t)grow*3;
        const float x = opt[row_l*25 + p*3+0] + cx - T[0];
        const float y = opt[row_l*25 + p*3+1] + cy - T[1];
        const float z = opt[row_l*25 + p*3+2] + cz - T[2];
        const float rx = R[0]*x + R[3]*y + R[6]*z;
        const float ry = R[1]*x + R[4]*y + R[7]*z;
        const float rz = R[2]*x + R[5]*y + R[8]*z;
        const float nm = sqrtf(rx*rx + ry*ry + rz*rz + 1e-8f);
        const float vals[4] = {rx, ry, rz, nm};
        #pragma unroll
        for (int sl = 0; sl < 4; ++sl) {
            const int col = 192 + sl*96 + h*8 + p;
            const float vv = vals[sl];
            const unsigned int u = __float_as_uint(vv);
            const float hif = __uint_as_float(u & 0xFFFF0000u);
            feat_hi[(size_t)grow*576 + col] = (ushort_t)(u >> 16);
            feat_lo[(size_t)grow*576 + col] = (ushort_t)(__float_as_uint(vv - hif) >> 16);
        }
    }
}

// ===========================================================================
// Kernel 4: out0 = feat @ wout + bout via MFMA; out0 non-temporal stores.
// ===========================================================================
__global__ __launch_bounds__(256) void out_gemm_mfma_kernel(
    const ushort_t* __restrict__ feat_hi, const ushort_t* __restrict__ feat_lo,
    const ushort_t* __restrict__ wo_hi, const ushort_t* __restrict__ wo_lo,
    const float* __restrict__ bout, float* __restrict__ out0)
{
    const int blk = blockIdx.x;
    const int rt = blk / 6, ct = blk - rt*6;
    const int r0 = rt * 64, c0 = ct * 64;
    const int tid = threadIdx.x;
    const int wave = tid >> 6, lane = tid & 63;
    const int wrow = wave >> 1, wcol = wave & 1;
    const int m0 = r0 + wrow*32, n0 = c0 + wcol*32;
    const int qd = lane >> 4, lr = lane & 15;

    f32x4 acc[2][2] = {{{0,0,0,0},{0,0,0,0}},{{0,0,0,0},{0,0,0,0}}};

    const ushort_t* ah0 = feat_hi + (size_t)(m0 + lr)*576 + qd*8;
    const ushort_t* ah1 = ah0 + 16*576;
    const ushort_t* al0 = feat_lo + (size_t)(m0 + lr)*576 + qd*8;
    const ushort_t* al1 = al0 + 16*576;
    const ushort_t* bh0 = wo_hi + (size_t)(n0 + lr)*576 + qd*8;
    const ushort_t* bh1 = bh0 + 16*576;
    const ushort_t* bl0 = wo_lo + (size_t)(n0 + lr)*576 + qd*8;
    const ushort_t* bl1 = bl0 + 16*576;

    for (int kk = 0; kk < 576; kk += 32) {
        const bf16x8 fh0 = *(const bf16x8*)(ah0 + kk);
        const bf16x8 fh1 = *(const bf16x8*)(ah1 + kk);
        const bf16x8 fl0 = *(const bf16x8*)(al0 + kk);
        const bf16x8 fl1 = *(const bf16x8*)(al1 + kk);
        const bf16x8 wh0 = *(const bf16x8*)(bh0 + kk);
        const bf16x8 wh1 = *(const bf16x8*)(bh1 + kk);
        const bf16x8 wl0 = *(const bf16x8*)(bl0 + kk);
        const bf16x8 wl1 = *(const bf16x8*)(bl1 + kk);
        acc[0][0] = __builtin_amdgcn_mfma_f32_16x16x32_bf16(fh0, wh0, acc[0][0], 0, 0, 0);
        acc[0][1] = __builtin_amdgcn_mfma_f32_16x16x32_bf16(fh0, wh1, acc[0][1], 0, 0, 0);
        acc[1][0] = __builtin_amdgcn_mfma_f32_16x16x32_bf16(fh1, wh0, acc[1][0], 0, 0, 0);
        acc[1][1] = __builtin_amdgcn_mfma_f32_16x16x32_bf16(fh1, wh1, acc[1][1], 0, 0, 0);
        acc[0][0] = __builtin_amdgcn_mfma_f32_16x16x32_bf16(fl0, wh0, acc[0][0], 0, 0, 0);
        acc[0][1] = __builtin_amdgcn_mfma_f32_16x16x32_bf16(fl0, wh1, acc[0][1], 0, 0, 0);
        acc[1][0] = __builtin_amdgcn_mfma_f32_16x16x32_bf16(fl1, wh0, acc[1][0], 0, 0, 0);
        acc[1][1] = __builtin_amdgcn_mfma_f32_16x16x32_bf16(fl1, wh1, acc[1][1], 0, 0, 0);
        acc[0][0] = __builtin_amdgcn_mfma_f32_16x16x32_bf16(fh0, wl0, acc[0][0], 0, 0, 0);
        acc[0][1] = __builtin_amdgcn_mfma_f32_16x16x32_bf16(fh0, wl1, acc[0][1], 0, 0, 0);
        acc[1][0] = __builtin_amdgcn_mfma_f32_16x16x32_bf16(fh1, wl0, acc[1][0], 0, 0, 0);
        acc[1][1] = __builtin_amdgcn_mfma_f32_16x16x32_bf16(fh1, wl1, acc[1][1], 0, 0, 0);
    }

    #pragma unroll
    for (int mt = 0; mt < 2; ++mt) {
        #pragma unroll
        for (int nt = 0; nt < 2; ++nt) {
            const int col = n0 + nt*16 + lr;
            const float bb = bout[col];
            #pragma unroll
            for (int reg = 0; reg < 4; ++reg) {
                const int row = m0 + mt*16 + qd*4 + reg;
                __builtin_nontemporal_store(acc[mt][nt][reg] + bb,
                                            out0 + (size_t)row*CS + col);
            }
        }
    }
}

// ===========================================================================
extern "C" void kernel_launch(void* const* d_in, const int* in_sizes, int n_in,
                              void* d_out, int out_size, void* d_ws, size_t ws_size,
                              hipStream_t stream)
{
    const float* s     = (const float*)d_in[0];
    const float* rot   = (const float*)d_in[2];
    const float* trans = (const float*)d_in[3];
    const float* mask  = (const float*)d_in[4];
    const float* wq    = (const float*)d_in[5];
    const float* bq    = (const float*)d_in[6];
    const float* wkv   = (const float*)d_in[7];
    const float* bkv   = (const float*)d_in[8];
    const float* g_gamma = (const float*)d_in[9];
    const float* g_beta  = (const float*)d_in[10];
    const float* wgq   = (const float*)d_in[11];
    const float* bgq   = (const float*)d_in[12];
    const float* wgk   = (const float*)d_in[13];
    const float* bgk   = (const float*)d_in[14];
    const float* wqp   = (const float*)d_in[15];
    const float* bqp   = (const float*)d_in[16];
    const float* wkvp  = (const float*)d_in[17];
    const float* bkvp  = (const float*)d_in[18];
    const float* head_weights = (const float*)d_in[19];
    const float* wdist = (const float*)d_in[20];
    const float* bdist = (const float*)d_in[21];
    const float* wout  = (const float*)d_in[22];
    const float* bout  = (const float*)d_in[23];

    float* ws      = (float*)d_ws;
    float* q_buf   = ws + 0;
    float* gq_buf  = ws + 983040;
    float* gk_buf  = ws + 1032192;
    float* k_buf   = ws + 1081344;
    float* v_buf   = ws + 1474560;
    ushort_t* sgn_bf  = (ushort_t*)(ws + 1867776);
    ushort_t* feat_hi = (ushort_t*)(ws + 2457600);
    ushort_t* feat_lo = (ushort_t*)(ws + 3047424);
    ushort_t* wo_hi   = (ushort_t*)(ws + 3637248);
    ushort_t* wo_lo   = (ushort_t*)(ws + 3747840);
    float*    rawp    = ws + 4194304;

    float* out0  = (float*)d_out;
    float* a_out = out0 + 786432;
    ushort_t* s_bf   = (ushort_t*)(a_out);
    ushort_t* wt_bf  = (ushort_t*)(a_out + 393216);
    ushort_t* wtg_bf = (ushort_t*)(a_out + 614400);
    float*    pbias  = a_out + 688128;
    float*    gbias  = a_out + 689280;

    convert_ln_kernel<<<1223, 256, 0, stream>>>(s, wq, bq, wkv, bkv, wqp, bqp,
                                                wkvp, bkvp, wgq, bgq, wgk, bgk,
                                                wout, g_gamma, g_beta,
                                                s_bf, wt_bf, wtg_bf, pbias, gbias,
                                                wo_hi, wo_lo, sgn_bf);
    proj_ggemm_kernel<<<600, 256, 0, stream>>>(s_bf, wt_bf, pbias,
                                               sgn_bf, wtg_bf, gbias,
                                               q_buf, k_buf, v_buf, rawp,
                                               gq_buf, gk_buf);
    attn_mfma_kernel<<<384, 256, 0, stream>>>(q_buf, k_buf, rawp, rot,
                                              gq_buf, gk_buf, trans, mask,
                                              head_weights, wdist, bdist, a_out);
    out_feat_mfma_kernel<<<384, 256, 0, stream>>>(a_out, v_buf, rawp, rot, trans,
                                                  feat_hi, feat_lo);
    out_gemm_mfma_kernel<<<192, 256, 0, stream>>>(feat_hi, feat_lo, wo_hi, wo_lo,
                                                  bout, out0);
}